// Round 1
// baseline (541.746 us; speedup 1.0000x reference)
//
#include <hip/hip_runtime.h>
#include <hip/hip_bf16.h>

#define N_NODES 100000
#define N_EDGES 1600000
#define DIM 64

// ---------------------------------------------------------------------------
// 1) init: zero the accumulator (d_out) and set deg = 1.0 (self-loop)
// ---------------------------------------------------------------------------
__global__ __launch_bounds__(256) void init_kernel(float* __restrict__ out,
                                                   float* __restrict__ deg) {
    int i = blockIdx.x * 256 + threadIdx.x;
    int total = N_NODES * DIM;
    if (i < total) out[i] = 0.0f;
    if (i < N_NODES) deg[i] = 1.0f;
}

// ---------------------------------------------------------------------------
// 2) degree: deg[col[e]] += 1
// ---------------------------------------------------------------------------
__global__ __launch_bounds__(256) void deg_kernel(const int* __restrict__ col,
                                                  float* __restrict__ deg) {
    int e = blockIdx.x * 256 + threadIdx.x;
    if (e < N_EDGES) atomicAdd(&deg[col[e]], 1.0f);
}

// ---------------------------------------------------------------------------
// 3) dinv = rsqrt(deg), in place
// ---------------------------------------------------------------------------
__global__ __launch_bounds__(256) void dinv_kernel(float* __restrict__ deg) {
    int i = blockIdx.x * 256 + threadIdx.x;
    if (i < N_NODES) deg[i] = rsqrtf(deg[i]);
}

// ---------------------------------------------------------------------------
// 4) s[n][j] = dinv[n] * sum_k x[n][k] * W[j][k]
//    wave-per-row; W staged transposed in LDS (lane j reads Wl[k*64+j] ->
//    consecutive addresses, conflict-free); x row broadcast via __shfl.
// ---------------------------------------------------------------------------
__global__ __launch_bounds__(256) void gemm_kernel(const float* __restrict__ x,
                                                   const float* __restrict__ W,
                                                   const float* __restrict__ dinv,
                                                   float* __restrict__ s) {
    __shared__ float Wl[DIM * DIM];
    for (int idx = threadIdx.x; idx < DIM * DIM; idx += 256) {
        int j = idx >> 6;
        int k = idx & 63;
        Wl[k * DIM + j] = W[idx];  // transpose: Wl[k][j] = W[j][k]
    }
    __syncthreads();

    const int wave = threadIdx.x >> 6;
    const int lane = threadIdx.x & 63;
    const int waves_total = gridDim.x * 4;

    for (int n = blockIdx.x * 4 + wave; n < N_NODES; n += waves_total) {
        float xv = x[n * DIM + lane];
        float acc = 0.0f;
#pragma unroll
        for (int k = 0; k < DIM; ++k) {
            float xk = __shfl(xv, k);
            acc = fmaf(xk, Wl[k * DIM + lane], acc);
        }
        s[n * DIM + lane] = acc * dinv[n];
    }
}

// ---------------------------------------------------------------------------
// 5) scatter: wave-per-edge, out[col] += s[row]  (coalesced 256B per wave)
// ---------------------------------------------------------------------------
__global__ __launch_bounds__(256) void scatter_kernel(const int* __restrict__ row,
                                                      const int* __restrict__ col,
                                                      const float* __restrict__ s,
                                                      float* __restrict__ out) {
    int e = blockIdx.x * 4 + (threadIdx.x >> 6);
    if (e >= N_EDGES) return;
    int lane = threadIdx.x & 63;
    int r = row[e];  // broadcast load (all lanes same addr)
    int c = col[e];
    atomicAdd(&out[c * DIM + lane], s[r * DIM + lane]);
}

// ---------------------------------------------------------------------------
// 6) finalize: out = relu(dinv[n] * (out + s) + b)
// ---------------------------------------------------------------------------
__global__ __launch_bounds__(256) void final_kernel(float* __restrict__ out,
                                                    const float* __restrict__ s,
                                                    const float* __restrict__ dinv,
                                                    const float* __restrict__ b) {
    int i = blockIdx.x * 256 + threadIdx.x;
    int total = N_NODES * DIM;
    if (i >= total) return;
    int n = i >> 6;
    int j = i & 63;
    float v = fmaf(dinv[n], out[i] + s[i], b[j]);
    out[i] = fmaxf(v, 0.0f);
}

extern "C" void kernel_launch(void* const* d_in, const int* in_sizes, int n_in,
                              void* d_out, int out_size, void* d_ws, size_t ws_size,
                              hipStream_t stream) {
    const float* x    = (const float*)d_in[0];
    const int*   ei   = (const int*)d_in[1];   // [2, E] int32
    const float* W    = (const float*)d_in[2];
    const float* b    = (const float*)d_in[3];
    float*       out  = (float*)d_out;

    const int* row = ei;            // source nodes
    const int* col = ei + N_EDGES;  // target nodes

    // workspace layout: deg/dinv [N] floats, then s [N*DIM] floats (~26 MB)
    float* deg = (float*)d_ws;
    float* s   = deg + N_NODES;  // 400000 B offset, 16B-aligned

    const int total = N_NODES * DIM;

    init_kernel<<<(total + 255) / 256, 256, 0, stream>>>(out, deg);
    deg_kernel<<<(N_EDGES + 255) / 256, 256, 0, stream>>>(col, deg);
    dinv_kernel<<<(N_NODES + 255) / 256, 256, 0, stream>>>(deg);
    gemm_kernel<<<2048, 256, 0, stream>>>(x, W, deg, s);
    scatter_kernel<<<(N_EDGES + 3) / 4, 256, 0, stream>>>(row, col, s, out);
    final_kernel<<<(total + 255) / 256, 256, 0, stream>>>(out, s, deg, b);
}

// Round 2
// 385.234 us; speedup vs baseline: 1.4063x; 1.4063x over previous
//
#include <hip/hip_runtime.h>
#include <hip/hip_bf16.h>

#define N_NODES 100000
#define N_EDGES 1600000
#define DIM 64
#define NBLK 391  // ceil(N_NODES / 256)

// ---------------------------------------------------------------------------
// 1) zero the histogram
// ---------------------------------------------------------------------------
__global__ __launch_bounds__(256) void zero_kernel(int* __restrict__ counts) {
    int i = blockIdx.x * 256 + threadIdx.x;
    if (i < N_NODES) counts[i] = 0;
}

// ---------------------------------------------------------------------------
// 2) histogram: counts[col[e]]++  (this IS the degree minus self-loop)
// ---------------------------------------------------------------------------
__global__ __launch_bounds__(256) void hist_kernel(const int* __restrict__ col,
                                                   int* __restrict__ counts) {
    int e = blockIdx.x * 256 + threadIdx.x;
    if (e < N_EDGES) atomicAdd(&counts[col[e]], 1);
}

// ---------------------------------------------------------------------------
// 3) scan step 1: per-block exclusive scan of counts -> offsets, block totals
// ---------------------------------------------------------------------------
__global__ __launch_bounds__(256) void scan1_kernel(const int* __restrict__ counts,
                                                    int* __restrict__ offsets,
                                                    int* __restrict__ blocksums) {
    __shared__ int tmp[256];
    int gid = blockIdx.x * 256 + threadIdx.x;
    int v = (gid < N_NODES) ? counts[gid] : 0;
    tmp[threadIdx.x] = v;
    __syncthreads();
    for (int off = 1; off < 256; off <<= 1) {
        int t = (threadIdx.x >= off) ? tmp[threadIdx.x - off] : 0;
        __syncthreads();
        tmp[threadIdx.x] += t;
        __syncthreads();
    }
    if (gid < N_NODES) offsets[gid] = tmp[threadIdx.x] - v;  // exclusive
    if (threadIdx.x == 255) blocksums[blockIdx.x] = tmp[255];
}

// ---------------------------------------------------------------------------
// 4) scan step 2: single-block exclusive scan of the 391 block sums
// ---------------------------------------------------------------------------
__global__ __launch_bounds__(512) void scan2_kernel(int* __restrict__ blocksums) {
    __shared__ int tmp[512];
    int tid = threadIdx.x;
    int v = (tid < NBLK) ? blocksums[tid] : 0;
    tmp[tid] = v;
    __syncthreads();
    for (int off = 1; off < 512; off <<= 1) {
        int t = (tid >= off) ? tmp[tid - off] : 0;
        __syncthreads();
        tmp[tid] += t;
        __syncthreads();
    }
    if (tid < NBLK) blocksums[tid] = tmp[tid] - v;  // exclusive
}

// ---------------------------------------------------------------------------
// 5) scan step 3: add block prefix, copy to cursor, compute dinv
// ---------------------------------------------------------------------------
__global__ __launch_bounds__(256) void scan3_kernel(const int* __restrict__ counts,
                                                    int* __restrict__ offsets,
                                                    const int* __restrict__ blocksums,
                                                    int* __restrict__ cursor,
                                                    float* __restrict__ dinv) {
    int gid = blockIdx.x * 256 + threadIdx.x;
    if (gid < N_NODES) {
        int off = offsets[gid] + blocksums[blockIdx.x];
        offsets[gid] = off;
        cursor[gid] = off;
        dinv[gid] = rsqrtf((float)(counts[gid] + 1));  // +1 self-loop
    }
    if (gid == 0) offsets[N_NODES] = N_EDGES;
}

// ---------------------------------------------------------------------------
// 6) s[n][j] = dinv[n] * sum_k x[n][k] * W[j][k]   (wave-per-row)
// ---------------------------------------------------------------------------
__global__ __launch_bounds__(256) void gemm_kernel(const float* __restrict__ x,
                                                   const float* __restrict__ W,
                                                   const float* __restrict__ dinv,
                                                   float* __restrict__ s) {
    __shared__ float Wl[DIM * DIM];
    for (int idx = threadIdx.x; idx < DIM * DIM; idx += 256) {
        int j = idx >> 6;
        int k = idx & 63;
        Wl[k * DIM + j] = W[idx];  // transpose: Wl[k][j] = W[j][k]
    }
    __syncthreads();

    const int wave = threadIdx.x >> 6;
    const int lane = threadIdx.x & 63;
    const int waves_total = gridDim.x * 4;

    for (int n = blockIdx.x * 4 + wave; n < N_NODES; n += waves_total) {
        float xv = x[n * DIM + lane];
        float acc = 0.0f;
#pragma unroll
        for (int k = 0; k < DIM; ++k) {
            float xk = __shfl(xv, k);
            acc = fmaf(xk, Wl[k * DIM + lane], acc);
        }
        s[n * DIM + lane] = acc * dinv[n];
    }
}

// ---------------------------------------------------------------------------
// 7) bucket-scatter: sorted_row[cursor[col[e]]++] = row[e]
// ---------------------------------------------------------------------------
__global__ __launch_bounds__(256) void sort_kernel(const int* __restrict__ row,
                                                   const int* __restrict__ col,
                                                   int* __restrict__ cursor,
                                                   int* __restrict__ sorted_row) {
    int e = blockIdx.x * 256 + threadIdx.x;
    if (e < N_EDGES) {
        int c = col[e];
        int pos = atomicAdd(&cursor[c], 1);
        sorted_row[pos] = row[e];
    }
}

// ---------------------------------------------------------------------------
// 8) aggregate + finalize: wave-per-node, register accumulation, no atomics
//    out[n] = relu(dinv[n] * (sum_{r in nbrs(n)} s[r] + s[n]) + b)
// ---------------------------------------------------------------------------
__global__ __launch_bounds__(256) void agg_kernel(const int* __restrict__ offsets,
                                                  const int* __restrict__ sorted_row,
                                                  const float* __restrict__ s,
                                                  const float* __restrict__ dinv,
                                                  const float* __restrict__ b,
                                                  float* __restrict__ out) {
    int n = blockIdx.x * 4 + (threadIdx.x >> 6);
    if (n >= N_NODES) return;
    int lane = threadIdx.x & 63;
    int start = offsets[n];
    int end = offsets[n + 1];

    float acc = s[(size_t)n * DIM + lane];  // self-loop term
    int p = start;
    for (; p + 2 <= end; p += 2) {
        int r0 = sorted_row[p];
        int r1 = sorted_row[p + 1];
        float v0 = s[(size_t)r0 * DIM + lane];
        float v1 = s[(size_t)r1 * DIM + lane];
        acc += v0;
        acc += v1;
    }
    if (p < end) acc += s[(size_t)sorted_row[p] * DIM + lane];

    float v = fmaf(dinv[n], acc, b[lane]);
    out[n * DIM + lane] = fmaxf(v, 0.0f);
}

extern "C" void kernel_launch(void* const* d_in, const int* in_sizes, int n_in,
                              void* d_out, int out_size, void* d_ws, size_t ws_size,
                              hipStream_t stream) {
    const float* x   = (const float*)d_in[0];
    const int*   ei  = (const int*)d_in[1];  // [2, E] int32
    const float* W   = (const float*)d_in[2];
    const float* b   = (const float*)d_in[3];
    float*       out = (float*)d_out;

    const int* row = ei;            // source nodes
    const int* col = ei + N_EDGES;  // target nodes

    // workspace layout (bytes, 256-aligned):
    //   counts     int[100000]      @ 0          (400000)
    //   offsets    int[100001]      @ 400128     (400004)
    //   cursor     int[100000]      @ 800256     (400000)
    //   dinv       float[100000]    @ 1200384    (400000)
    //   blocksums  int[512]         @ 1600512    (2048)
    //   sorted_row int[1600000]     @ 1602816    (6400000)
    //   s          float[6400000]   @ 8002816    (25600000)  -> end ~33.6 MB
    char* ws = (char*)d_ws;
    int*   counts     = (int*)(ws + 0);
    int*   offsets    = (int*)(ws + 400128);
    int*   cursor     = (int*)(ws + 800256);
    float* dinv       = (float*)(ws + 1200384);
    int*   blocksums  = (int*)(ws + 1600512);
    int*   sorted_row = (int*)(ws + 1602816);
    float* s          = (float*)(ws + 8002816);

    zero_kernel<<<NBLK, 256, 0, stream>>>(counts);
    hist_kernel<<<(N_EDGES + 255) / 256, 256, 0, stream>>>(col, counts);
    scan1_kernel<<<NBLK, 256, 0, stream>>>(counts, offsets, blocksums);
    scan2_kernel<<<1, 512, 0, stream>>>(blocksums);
    scan3_kernel<<<NBLK, 256, 0, stream>>>(counts, offsets, blocksums, cursor, dinv);
    gemm_kernel<<<2048, 256, 0, stream>>>(x, W, dinv, s);
    sort_kernel<<<(N_EDGES + 255) / 256, 256, 0, stream>>>(row, col, cursor, sorted_row);
    agg_kernel<<<(N_NODES + 3) / 4, 256, 0, stream>>>(offsets, sorted_row, s, dinv, b, out);
}